// Round 10
// baseline (843.277 us; speedup 1.0000x reference)
//
#include <hip/hip_runtime.h>
#include <math.h>

// Problem constants
#define B_  16
#define F_  8
#define C_  8
#define G_  32
#define G3_ 32768
#define P_  4
#define N_  (B_*F_*C_*G3_)
#define SF_ (C_*G3_)
#define SB_ (F_*SF_)
#define APACK_SZ (P_*F_*9*64*8)

typedef __attribute__((ext_vector_type(8))) short short8v;
typedef __attribute__((ext_vector_type(4))) float f32x4;
typedef unsigned short u16;
typedef unsigned int u32;

__device__ __constant__ int c_k[8][8] = {
  {0,1,2,3,4,5,6,7},
  {1,0,4,5,2,3,7,6},
  {2,4,0,6,1,7,3,5},
  {3,5,6,0,7,1,2,4},
  {4,2,1,7,0,6,5,3},
  {5,3,7,1,6,0,4,2},
  {6,7,3,2,5,4,0,1},
  {7,6,5,4,3,2,1,0}};
__device__ __constant__ float c_s[8][8] = {
  { 1, 1, 1, 1,-1,-1,-1,-1},
  { 1, 1, 1, 1,-1,-1,-1,-1},
  { 1,-1, 1, 1, 1, 1,-1, 1},
  { 1,-1,-1, 1,-1, 1, 1,-1},
  { 1,-1, 1, 1, 1, 1,-1, 1},
  { 1,-1,-1, 1,-1, 1, 1,-1},
  { 1, 1,-1, 1, 1,-1, 1, 1},
  { 1, 1,-1, 1, 1,-1, 1, 1}};

__device__ __forceinline__ float fast_tanh(float v) {
  float e = __expf(2.f * v);
  return 1.f - 2.f / (e + 1.f);
}
__device__ __forceinline__ float fast_sig(float v) {
  return 1.f / (1.f + __expf(-v));
}
__device__ __forceinline__ u32 bf16_rne(float v) {
  u32 u = __float_as_uint(v);
  return (u + 0x7FFFu + ((u >> 16) & 1u)) >> 16;
}
__device__ __forceinline__ u32 pk_bf16(float a, float b) {
  u32 d;
  asm("v_cvt_pk_bf16_f32 %0, %1, %2" : "=v"(d) : "v"(a), "v"(b));
  return d;
}
__device__ __forceinline__ float bl(u32 u) { return __uint_as_float(u << 16); }
__device__ __forceinline__ float bh(u32 u) { return __uint_as_float(u & 0xffff0000u); }
__device__ __forceinline__ float b16f(u16 v) { return __uint_as_float(((u32)v) << 16); }

// position swizzle: quad qq of point pt stored at (qq ^ HS(pt)); HS(pt+16)==HS(pt)
#define HS(pt) (((pt) + ((pt) >> 2)) & 3)

// ---------------------------------------------------------------------------
// prep: A fragments in per-lane MFMA layout + softmax mix (R8 layout)
__global__ void prep_kernel(const float* __restrict__ all_weights,
                            const float* __restrict__ mix_logits,
                            u16* __restrict__ Apack,
                            float* __restrict__ mix) {
  int idx = blockIdx.x * 256 + threadIdx.x;
  if (idx < APACK_SZ) {
    int e = idx & 7;
    int l = (idx >> 3) & 63;
    int rest = idx >> 9;
    int t = rest % 9;
    int fp = rest / 9;
    int f = fp & 7, p = fp >> 3;
    int g = l >> 4, m = l & 15;
    int zoff = m >> 3, i = m & 7;
    int kk = g*4 + (e & 3) + ((e >= 4) ? 16 : 0);
    int zl = kk >> 3, j = kk & 7;
    int dz = zl - zoff;
    float val = 0.f;
    if (dz >= 0 && dz <= 2)
      val = c_s[i][j] * all_weights[((f*P_ + p)*27 + (dz*9 + t))*8 + c_k[i][j]];
    Apack[idx] = (u16)bf16_rne(val);
  }
  if (blockIdx.x == 0 && threadIdx.x < P_*F_) {
    int p = threadIdx.x / F_, g = threadIdx.x % F_;
    const float* row = &mix_logits[(p*F_ + g)*F_];
    float mx = row[0];
    for (int f = 1; f < F_; ++f) mx = fmaxf(mx, row[f]);
    float e[F_]; float sum = 0.f;
    for (int f = 0; f < F_; ++f) { e[f] = __expf(row[f] - mx); sum += e[f]; }
    float inv = 1.f / sum;
    for (int f = 0; f < F_; ++f) mix[(p*F_ + g)*F_ + f] = e[f] * inv;
  }
}

// ---------------------------------------------------------------------------
// Fused conv+tanh+mix(+gate).  Block: (b, z-pair, y-tile of 4), ALL 8 fields.
// Planar bf16 X layout [b][f][comp][z][y][x] (as R8).
// MODE 0: f32 in, bf16 out; 1: bf16->bf16; 2: bf16 in, gate, f32 out.
#define TPTS 204     // 6*34

template<int MODE>
__device__ __forceinline__ uint4 field_step(
    int f, const void* __restrict__ xsrc_, const u16* __restrict__ Apack,
    const float* __restrict__ biases, int p, int b, int z0, int y0,
    u32* xk, int tid, int lane, int wid, int g, int ln) {
  if (f) __syncthreads();       // prev field's LDS reads done before overwrite

  // ---- stage field f: 4 qq x 6 rows x 8 chunks of 4 x-points ----
  if (tid < 192) {
    int qq  = tid / 48;
    int r2  = tid - qq*48;
    int row = r2 >> 3;
    int c   = r2 & 7;
    int zl = qq >> 1, jq = qq & 1;
    int gz0 = z0 - 2 + zl;             // may be <0; gz0+2 always valid
    int gy  = y0 - 2 + row;            // may be <0
    int gx  = c * 4;
    int off = (jq*4)*G3_ + gz0*1024 + gy*32 + gx;
    int ptb = row*34 + 2 + gx;
    u32 d0[4], d1[4], d2[4], d3[4];
    if (MODE != 0) {
      const u16* s0 = (const u16*)xsrc_ + (size_t)b*SB_ + f*SF_ + off;
      const u16* s1 = s0 + 2048;
      uint2 a0={0,0},a1={0,0},a2={0,0},a3={0,0};
      uint2 e0={0,0},e1={0,0},e2={0,0},e3={0,0};
      if (gy >= 0) {
        if (gz0 >= 0) {
          a0 = *(const uint2*)(s0);
          a1 = *(const uint2*)(s0 + G3_);
          a2 = *(const uint2*)(s0 + 2*G3_);
          a3 = *(const uint2*)(s0 + 3*G3_);
        }
        e0 = *(const uint2*)(s1);
        e1 = *(const uint2*)(s1 + G3_);
        e2 = *(const uint2*)(s1 + 2*G3_);
        e3 = *(const uint2*)(s1 + 3*G3_);
      }
      d0[0] = __builtin_amdgcn_perm(a1.x, a0.x, 0x05040100u);
      d0[1] = __builtin_amdgcn_perm(a1.x, a0.x, 0x07060302u);
      d0[2] = __builtin_amdgcn_perm(a1.y, a0.y, 0x05040100u);
      d0[3] = __builtin_amdgcn_perm(a1.y, a0.y, 0x07060302u);
      d1[0] = __builtin_amdgcn_perm(a3.x, a2.x, 0x05040100u);
      d1[1] = __builtin_amdgcn_perm(a3.x, a2.x, 0x07060302u);
      d1[2] = __builtin_amdgcn_perm(a3.y, a2.y, 0x05040100u);
      d1[3] = __builtin_amdgcn_perm(a3.y, a2.y, 0x07060302u);
      d2[0] = __builtin_amdgcn_perm(e1.x, e0.x, 0x05040100u);
      d2[1] = __builtin_amdgcn_perm(e1.x, e0.x, 0x07060302u);
      d2[2] = __builtin_amdgcn_perm(e1.y, e0.y, 0x05040100u);
      d2[3] = __builtin_amdgcn_perm(e1.y, e0.y, 0x07060302u);
      d3[0] = __builtin_amdgcn_perm(e3.x, e2.x, 0x05040100u);
      d3[1] = __builtin_amdgcn_perm(e3.x, e2.x, 0x07060302u);
      d3[2] = __builtin_amdgcn_perm(e3.y, e2.y, 0x05040100u);
      d3[3] = __builtin_amdgcn_perm(e3.y, e2.y, 0x07060302u);
    } else {
      const float* s0 = (const float*)xsrc_ + (size_t)b*SB_ + f*SF_ + off;
      const float* s1 = s0 + 2048;
      float4 A0={0,0,0,0},A1={0,0,0,0},A2={0,0,0,0},A3={0,0,0,0};
      float4 B0={0,0,0,0},B1={0,0,0,0},B2={0,0,0,0},B3={0,0,0,0};
      if (gy >= 0) {
        if (gz0 >= 0) {
          A0 = *(const float4*)(s0);
          A1 = *(const float4*)(s0 + G3_);
          A2 = *(const float4*)(s0 + 2*G3_);
          A3 = *(const float4*)(s0 + 3*G3_);
        }
        B0 = *(const float4*)(s1);
        B1 = *(const float4*)(s1 + G3_);
        B2 = *(const float4*)(s1 + 2*G3_);
        B3 = *(const float4*)(s1 + 3*G3_);
      }
      d0[0]=pk_bf16(A0.x,A1.x); d1[0]=pk_bf16(A2.x,A3.x);
      d2[0]=pk_bf16(B0.x,B1.x); d3[0]=pk_bf16(B2.x,B3.x);
      d0[1]=pk_bf16(A0.y,A1.y); d1[1]=pk_bf16(A2.y,A3.y);
      d2[1]=pk_bf16(B0.y,B1.y); d3[1]=pk_bf16(B2.y,B3.y);
      d0[2]=pk_bf16(A0.z,A1.z); d1[2]=pk_bf16(A2.z,A3.z);
      d2[2]=pk_bf16(B0.z,B1.z); d3[2]=pk_bf16(B2.z,B3.z);
      d0[3]=pk_bf16(A0.w,A1.w); d1[3]=pk_bf16(A2.w,A3.w);
      d2[3]=pk_bf16(B0.w,B1.w); d3[3]=pk_bf16(B2.w,B3.w);
    }
    #define STW(px) { \
      uint4 d; d.x = d0[px]; d.y = d1[px]; d.z = d2[px]; d.w = d3[px]; \
      int pt = ptb + px; \
      *(uint4*)&xk[pt*16 + ((qq ^ HS(pt)) << 2)] = d; }
    STW(0) STW(1) STW(2) STW(3)
    #undef STW
  }

  // A fragments for this field (overlaps barrier wait)
  short8v a[9];
  const u16* ap = Apack + (size_t)((p*8 + f) * 9) * 512;
  #pragma unroll
  for (int t = 0; t < 9; ++t)
    a[t] = *(const short8v*)(ap + (t*64 + lane)*8);

  __syncthreads();

  // ---- compute: wave wid owns y row wid, both x halves ----
  f32x4 acc0 = {0.f,0.f,0.f,0.f}, acc1 = {0.f,0.f,0.f,0.f};
  #pragma unroll
  for (int dy = 0; dy < 3; ++dy) {
    int prow = (wid + dy)*34;
    #pragma unroll
    for (int dx = 0; dx < 3; ++dx) {
      int t = dy*3 + dx;
      int pt0 = prow + ln + dx;
      int dwb = pt0*16 + ((g ^ HS(pt0)) << 2);
      short8v b0 = *(const short8v*)&xk[dwb];
      short8v b1 = *(const short8v*)&xk[dwb + 256];   // pt0+16: HS invariant
      acc0 = __builtin_amdgcn_mfma_f32_16x16x32_bf16(a[t], b0, acc0, 0, 0, 0);
      acc1 = __builtin_amdgcn_mfma_f32_16x16x32_bf16(a[t], b1, acc1, 0, 0, 0);
    }
  }

  const float* bb = biases + (f*P_ + p)*8 + (g & 1)*4;
  float b0v = bb[0], b1v = bb[1], b2v = bb[2], b3v = bb[3];
  uint4 yp;
  yp.x = pk_bf16(fast_tanh(acc0[0] + b0v), fast_tanh(acc0[1] + b1v));
  yp.y = pk_bf16(fast_tanh(acc0[2] + b2v), fast_tanh(acc0[3] + b3v));
  yp.z = pk_bf16(fast_tanh(acc1[0] + b0v), fast_tanh(acc1[1] + b1v));
  yp.w = pk_bf16(fast_tanh(acc1[2] + b2v), fast_tanh(acc1[3] + b3v));
  return yp;
}

template<int MODE>
__global__ __launch_bounds__(256, 6)
void fused_kernel(const void* __restrict__ xsrc_,
                  void* __restrict__ xdst_,
                  const float* __restrict__ state,
                  const u16* __restrict__ Apack,
                  const float* __restrict__ biases,
                  const float* __restrict__ mixb,
                  const float* __restrict__ pal,
                  const float* __restrict__ gw,
                  const float* __restrict__ gb,
                  int p) {
  __shared__ __align__(16) u32 xk[TPTS * 16];     // 13056 B
  __shared__ __align__(16) u32 obuf[4][576];      // 9216 B per-wave store buffers

  // XCD-aware swizzle: give each XCD a contiguous (b,zt,yt) chunk so both
  // z- and y-halo neighbor blocks share that XCD's L2.  2048 % 8 == 0.
  int orig = blockIdx.x;
  int bid  = (orig & 7) * 256 + (orig >> 3);
  int yt = bid & 7;
  int zt = (bid >> 3) & 15;
  int b  =  bid >> 7;
  int z0 = zt * 2, y0 = yt * 4;
  int tid  = threadIdx.x;
  int lane = tid & 63;
  int wid  = tid >> 6;
  int g    = lane >> 4;
  int ln   = lane & 15;

  // zero x-halo points (x'=0,1): 6 rows x 2 pts x 16 dwords = 192
  if (tid < 192) {
    int pt = (tid >> 5) * 34 + ((tid >> 4) & 1);
    xk[pt*16 + (tid & 15)] = 0u;
  }

  uint4 yp0 = field_step<MODE>(0, xsrc_, Apack, biases, p, b, z0, y0, xk, tid, lane, wid, g, ln);
  uint4 yp1 = field_step<MODE>(1, xsrc_, Apack, biases, p, b, z0, y0, xk, tid, lane, wid, g, ln);
  uint4 yp2 = field_step<MODE>(2, xsrc_, Apack, biases, p, b, z0, y0, xk, tid, lane, wid, g, ln);
  uint4 yp3 = field_step<MODE>(3, xsrc_, Apack, biases, p, b, z0, y0, xk, tid, lane, wid, g, ln);
  uint4 yp4 = field_step<MODE>(4, xsrc_, Apack, biases, p, b, z0, y0, xk, tid, lane, wid, g, ln);
  uint4 yp5 = field_step<MODE>(5, xsrc_, Apack, biases, p, b, z0, y0, xk, tid, lane, wid, g, ln);
  uint4 yp6 = field_step<MODE>(6, xsrc_, Apack, biases, p, b, z0, y0, xk, tid, lane, wid, g, ln);
  uint4 yp7 = field_step<MODE>(7, xsrc_, Apack, biases, p, b, z0, y0, xk, tid, lane, wid, g, ln);

  // ---- epilogue: unpack y, 8x8 mix, residual (+gate) ----
  float yf[8][8];
  #define UNP(F, YPV) \
    yf[F][0]=bl(YPV.x); yf[F][1]=bh(YPV.x); yf[F][2]=bl(YPV.y); yf[F][3]=bh(YPV.y); \
    yf[F][4]=bl(YPV.z); yf[F][5]=bh(YPV.z); yf[F][6]=bl(YPV.w); yf[F][7]=bh(YPV.w);
  UNP(0,yp0) UNP(1,yp1) UNP(2,yp2) UNP(3,yp3)
  UNP(4,yp4) UNP(5,yp5) UNP(6,yp6) UNP(7,yp7)
  #undef UNP

  float alpha = fast_sig(pal[p]);
  float na = 1.f - alpha;
  int zoff = g >> 1;
  int i0 = (g & 1)*4;
  size_t ebase = (size_t)b*SB_ + (size_t)(z0 + zoff)*1024 + (size_t)(y0 + wid)*32 + ln;

  // store-phase role of this lane: row = comp*2+z (16 rows), 4 lanes/row
  u16*   ob16 = (u16*)&obuf[wid][0];     // rows of 32 u16 (64 B)
  float* ob32 = (float*)&obuf[wid][0];   // rows of 36 f32 (144 B, swizzle-friendly)
  int srow = lane >> 2;
  int sc   = srow >> 1, sz = srow & 1;
  int sx   = (lane & 3) * 8;
  size_t sbase = (size_t)b*SB_ + (size_t)sc*G3_ + (size_t)(z0 + sz)*1024
               + (size_t)(y0 + wid)*32 + sx;

  #pragma unroll
  for (int gg = 0; gg < 8; ++gg) {
    const float* mr = mixb + (p*8 + gg)*8;
    float o[8] = {0.f,0.f,0.f,0.f,0.f,0.f,0.f,0.f};
    #pragma unroll
    for (int f = 0; f < 8; ++f) {
      float m = mr[f];
      #pragma unroll
      for (int e = 0; e < 8; ++e) o[e] = fmaf(m, yf[f][e], o[e]);
    }
    size_t og = ebase + (size_t)gg*SF_;

    float xb[8];
    if (MODE == 0) {
      #pragma unroll
      for (int e = 0; e < 8; ++e)
        xb[e] = ((const float*)xsrc_)[og + (size_t)(i0 + (e & 3))*G3_ + ((e >> 2) << 4)];
    } else {
      #pragma unroll
      for (int e = 0; e < 8; ++e)
        xb[e] = b16f(((const u16*)xsrc_)[og + (size_t)(i0 + (e & 3))*G3_ + ((e >> 2) << 4)]);
    }

    if (MODE == 2) {
      #pragma unroll
      for (int e = 0; e < 8; ++e) {
        size_t idx = og + (size_t)(i0 + (e & 3))*G3_ + ((e >> 2) << 4);
        float xf = alpha*xb[e] + na*o[e];
        float st = state[idx];
        float w  = gw[gg*8 + i0 + (e & 3)];
        float bv = gb[gg*8 + i0 + (e & 3)];
        float gt = fast_sig(w*st + bv);
        ob32[((i0 + (e & 3))*2 + zoff)*36 + ln + ((e >> 2) << 4)] = gt*st + (1.f - gt)*xf;
      }
      // wave-local LDS ops are in-order; read back row-linear, store dense
      float4 v0 = *(const float4*)&ob32[srow*36 + sx];
      float4 v1 = *(const float4*)&ob32[srow*36 + sx + 4];
      float* op = (float*)xdst_ + sbase + (size_t)gg*SF_;
      *(float4*)(op)     = v0;
      *(float4*)(op + 4) = v1;
    } else {
      #pragma unroll
      for (int e = 0; e < 8; ++e) {
        float xf = alpha*xb[e] + na*o[e];
        ob16[((i0 + (e & 3))*2 + zoff)*32 + ln + ((e >> 2) << 4)] = (u16)bf16_rne(xf);
      }
      uint4 v = *(const uint4*)&ob16[srow*32 + sx];
      *(uint4*)((u16*)xdst_ + sbase + (size_t)gg*SF_) = v;
    }
  }
}

// ---------------------------------------------------------------------------
extern "C" void kernel_launch(void* const* d_in, const int* in_sizes, int n_in,
                              void* d_out, int out_size, void* d_ws, size_t ws_size,
                              hipStream_t stream) {
  (void)in_sizes; (void)n_in; (void)out_size; (void)ws_size;
  const float* state       = (const float*)d_in[0];
  const float* all_weights = (const float*)d_in[1];
  const float* all_biases  = (const float*)d_in[2];
  const float* mix_logits  = (const float*)d_in[3];
  const float* pal         = (const float*)d_in[4];
  const float* gw          = (const float*)d_in[5];
  const float* gb          = (const float*)d_in[6];
  float* out = (float*)d_out;

  // ws: X0 bf16 (N_) | X1 bf16 (N_) | Apack | mix
  u16* X0 = (u16*)d_ws;
  u16* X1 = X0 + N_;
  u16* Apack = X1 + N_;
  float* mixb = (float*)(Apack + APACK_SZ);

  prep_kernel<<<dim3(APACK_SZ/256), dim3(256), 0, stream>>>(
      all_weights, mix_logits, Apack, mixb);

  dim3 grid(2048), blk(256);
  // p0: state(f32) -> X0 ; p1: X0 -> X1 ; p2: X1 -> X0 ; p3: X0 (+state) -> out
  fused_kernel<0><<<grid, blk, 0, stream>>>((const void*)state, (void*)X0, state,
      Apack, all_biases, mixb, pal, gw, gb, 0);
  fused_kernel<1><<<grid, blk, 0, stream>>>((const void*)X0, (void*)X1, state,
      Apack, all_biases, mixb, pal, gw, gb, 1);
  fused_kernel<1><<<grid, blk, 0, stream>>>((const void*)X1, (void*)X0, state,
      Apack, all_biases, mixb, pal, gw, gb, 2);
  fused_kernel<2><<<grid, blk, 0, stream>>>((const void*)X0, (void*)out, state,
      Apack, all_biases, mixb, pal, gw, gb, 3);
}

// Round 11
// 305.755 us; speedup vs baseline: 2.7580x; 2.7580x over previous
//
#include <hip/hip_runtime.h>
#include <math.h>

// Problem constants
#define B_  16
#define F_  8
#define C_  8
#define G_  32
#define G3_ 32768
#define P_  4
#define N_  (B_*F_*C_*G3_)
#define SF_ (C_*G3_)
#define SB_ (F_*SF_)
#define APACK_SZ (P_*F_*9*64*8)

typedef __attribute__((ext_vector_type(8))) short short8v;
typedef __attribute__((ext_vector_type(4))) float f32x4;
typedef unsigned short u16;
typedef unsigned int u32;

__device__ __constant__ int c_k[8][8] = {
  {0,1,2,3,4,5,6,7},
  {1,0,4,5,2,3,7,6},
  {2,4,0,6,1,7,3,5},
  {3,5,6,0,7,1,2,4},
  {4,2,1,7,0,6,5,3},
  {5,3,7,1,6,0,4,2},
  {6,7,3,2,5,4,0,1},
  {7,6,5,4,3,2,1,0}};
__device__ __constant__ float c_s[8][8] = {
  { 1, 1, 1, 1,-1,-1,-1,-1},
  { 1, 1, 1, 1,-1,-1,-1,-1},
  { 1,-1, 1, 1, 1, 1,-1, 1},
  { 1,-1,-1, 1,-1, 1, 1,-1},
  { 1,-1, 1, 1, 1, 1,-1, 1},
  { 1,-1,-1, 1,-1, 1, 1,-1},
  { 1, 1,-1, 1, 1,-1, 1, 1},
  { 1, 1,-1, 1, 1,-1, 1, 1}};

__device__ __forceinline__ float fast_tanh(float v) {
  float e = __expf(2.f * v);
  return 1.f - 2.f / (e + 1.f);
}
__device__ __forceinline__ float fast_sig(float v) {
  return 1.f / (1.f + __expf(-v));
}
__device__ __forceinline__ u32 bf16_rne(float v) {
  u32 u = __float_as_uint(v);
  return (u + 0x7FFFu + ((u >> 16) & 1u)) >> 16;
}
__device__ __forceinline__ u32 pk_bf16(float a, float b) {
  u32 d;
  asm("v_cvt_pk_bf16_f32 %0, %1, %2" : "=v"(d) : "v"(a), "v"(b));
  return d;
}
__device__ __forceinline__ float bl(u32 u) { return __uint_as_float(u << 16); }
__device__ __forceinline__ float bh(u32 u) { return __uint_as_float(u & 0xffff0000u); }
__device__ __forceinline__ float b16f(u16 v) { return __uint_as_float(((u32)v) << 16); }

// position swizzle: quad qq of point pt stored at (qq ^ HS(pt)); HS(pt+16)==HS(pt)
#define HS(pt) (((pt) + ((pt) >> 2)) & 3)

// ---------------------------------------------------------------------------
// prep: A fragments in per-lane MFMA layout + softmax mix (R8 layout)
__global__ void prep_kernel(const float* __restrict__ all_weights,
                            const float* __restrict__ mix_logits,
                            u16* __restrict__ Apack,
                            float* __restrict__ mix) {
  int idx = blockIdx.x * 256 + threadIdx.x;
  if (idx < APACK_SZ) {
    int e = idx & 7;
    int l = (idx >> 3) & 63;
    int rest = idx >> 9;
    int t = rest % 9;
    int fp = rest / 9;
    int f = fp & 7, p = fp >> 3;
    int g = l >> 4, m = l & 15;
    int zoff = m >> 3, i = m & 7;
    int kk = g*4 + (e & 3) + ((e >= 4) ? 16 : 0);
    int zl = kk >> 3, j = kk & 7;
    int dz = zl - zoff;
    float val = 0.f;
    if (dz >= 0 && dz <= 2)
      val = c_s[i][j] * all_weights[((f*P_ + p)*27 + (dz*9 + t))*8 + c_k[i][j]];
    Apack[idx] = (u16)bf16_rne(val);
  }
  if (blockIdx.x == 0 && threadIdx.x < P_*F_) {
    int p = threadIdx.x / F_, g = threadIdx.x % F_;
    const float* row = &mix_logits[(p*F_ + g)*F_];
    float mx = row[0];
    for (int f = 1; f < F_; ++f) mx = fmaxf(mx, row[f]);
    float e[F_]; float sum = 0.f;
    for (int f = 0; f < F_; ++f) { e[f] = __expf(row[f] - mx); sum += e[f]; }
    float inv = 1.f / sum;
    for (int f = 0; f < F_; ++f) mix[(p*F_ + g)*F_ + f] = e[f] * inv;
  }
}

// ---------------------------------------------------------------------------
// Fused conv+tanh+mix(+gate).  Block: (b, z-pair, y-tile of 4), ALL 8 fields.
// Planar bf16 X layout [b][f][comp][z][y][x] (as R8).
// MODE 0: f32 in, bf16 out; 1: bf16->bf16; 2: bf16 in, gate, f32 out.
#define TPTS 204     // 6*34

template<int MODE>
__device__ __forceinline__ uint4 field_step(
    int f, const void* __restrict__ xsrc_, const u16* __restrict__ Apack,
    const float* __restrict__ biases, int p, int b, int z0, int y0,
    u32* xk, int tid, int lane, int wid, int g, int ln) {
  if (f) __syncthreads();       // prev field's LDS reads done before overwrite

  // ---- stage field f: 4 qq x 6 rows x 8 chunks of 4 x-points ----
  if (tid < 192) {
    int qq  = tid / 48;
    int r2  = tid - qq*48;
    int row = r2 >> 3;
    int c   = r2 & 7;
    int zl = qq >> 1, jq = qq & 1;
    int gz0 = z0 - 2 + zl;             // may be <0; gz0+2 always valid
    int gy  = y0 - 2 + row;            // may be <0
    int gx  = c * 4;
    int off = (jq*4)*G3_ + gz0*1024 + gy*32 + gx;
    int ptb = row*34 + 2 + gx;
    u32 d0[4], d1[4], d2[4], d3[4];
    if (MODE != 0) {
      const u16* s0 = (const u16*)xsrc_ + (size_t)b*SB_ + f*SF_ + off;
      const u16* s1 = s0 + 2048;
      uint2 a0={0,0},a1={0,0},a2={0,0},a3={0,0};
      uint2 e0={0,0},e1={0,0},e2={0,0},e3={0,0};
      if (gy >= 0) {
        if (gz0 >= 0) {
          a0 = *(const uint2*)(s0);
          a1 = *(const uint2*)(s0 + G3_);
          a2 = *(const uint2*)(s0 + 2*G3_);
          a3 = *(const uint2*)(s0 + 3*G3_);
        }
        e0 = *(const uint2*)(s1);
        e1 = *(const uint2*)(s1 + G3_);
        e2 = *(const uint2*)(s1 + 2*G3_);
        e3 = *(const uint2*)(s1 + 3*G3_);
      }
      d0[0] = __builtin_amdgcn_perm(a1.x, a0.x, 0x05040100u);
      d0[1] = __builtin_amdgcn_perm(a1.x, a0.x, 0x07060302u);
      d0[2] = __builtin_amdgcn_perm(a1.y, a0.y, 0x05040100u);
      d0[3] = __builtin_amdgcn_perm(a1.y, a0.y, 0x07060302u);
      d1[0] = __builtin_amdgcn_perm(a3.x, a2.x, 0x05040100u);
      d1[1] = __builtin_amdgcn_perm(a3.x, a2.x, 0x07060302u);
      d1[2] = __builtin_amdgcn_perm(a3.y, a2.y, 0x05040100u);
      d1[3] = __builtin_amdgcn_perm(a3.y, a2.y, 0x07060302u);
      d2[0] = __builtin_amdgcn_perm(e1.x, e0.x, 0x05040100u);
      d2[1] = __builtin_amdgcn_perm(e1.x, e0.x, 0x07060302u);
      d2[2] = __builtin_amdgcn_perm(e1.y, e0.y, 0x05040100u);
      d2[3] = __builtin_amdgcn_perm(e1.y, e0.y, 0x07060302u);
      d3[0] = __builtin_amdgcn_perm(e3.x, e2.x, 0x05040100u);
      d3[1] = __builtin_amdgcn_perm(e3.x, e2.x, 0x07060302u);
      d3[2] = __builtin_amdgcn_perm(e3.y, e2.y, 0x05040100u);
      d3[3] = __builtin_amdgcn_perm(e3.y, e2.y, 0x07060302u);
    } else {
      const float* s0 = (const float*)xsrc_ + (size_t)b*SB_ + f*SF_ + off;
      const float* s1 = s0 + 2048;
      float4 A0={0,0,0,0},A1={0,0,0,0},A2={0,0,0,0},A3={0,0,0,0};
      float4 B0={0,0,0,0},B1={0,0,0,0},B2={0,0,0,0},B3={0,0,0,0};
      if (gy >= 0) {
        if (gz0 >= 0) {
          A0 = *(const float4*)(s0);
          A1 = *(const float4*)(s0 + G3_);
          A2 = *(const float4*)(s0 + 2*G3_);
          A3 = *(const float4*)(s0 + 3*G3_);
        }
        B0 = *(const float4*)(s1);
        B1 = *(const float4*)(s1 + G3_);
        B2 = *(const float4*)(s1 + 2*G3_);
        B3 = *(const float4*)(s1 + 3*G3_);
      }
      d0[0]=pk_bf16(A0.x,A1.x); d1[0]=pk_bf16(A2.x,A3.x);
      d2[0]=pk_bf16(B0.x,B1.x); d3[0]=pk_bf16(B2.x,B3.x);
      d0[1]=pk_bf16(A0.y,A1.y); d1[1]=pk_bf16(A2.y,A3.y);
      d2[1]=pk_bf16(B0.y,B1.y); d3[1]=pk_bf16(B2.y,B3.y);
      d0[2]=pk_bf16(A0.z,A1.z); d1[2]=pk_bf16(A2.z,A3.z);
      d2[2]=pk_bf16(B0.z,B1.z); d3[2]=pk_bf16(B2.z,B3.z);
      d0[3]=pk_bf16(A0.w,A1.w); d1[3]=pk_bf16(A2.w,A3.w);
      d2[3]=pk_bf16(B0.w,B1.w); d3[3]=pk_bf16(B2.w,B3.w);
    }
    #define STW(px) { \
      uint4 d; d.x = d0[px]; d.y = d1[px]; d.z = d2[px]; d.w = d3[px]; \
      int pt = ptb + px; \
      *(uint4*)&xk[pt*16 + ((qq ^ HS(pt)) << 2)] = d; }
    STW(0) STW(1) STW(2) STW(3)
    #undef STW
  }

  // A fragments for this field (overlaps barrier wait)
  short8v a[9];
  const u16* ap = Apack + (size_t)((p*8 + f) * 9) * 512;
  #pragma unroll
  for (int t = 0; t < 9; ++t)
    a[t] = *(const short8v*)(ap + (t*64 + lane)*8);

  __syncthreads();

  // ---- compute: wave wid owns y row wid, both x halves ----
  f32x4 acc0 = {0.f,0.f,0.f,0.f}, acc1 = {0.f,0.f,0.f,0.f};
  #pragma unroll
  for (int dy = 0; dy < 3; ++dy) {
    int prow = (wid + dy)*34;
    #pragma unroll
    for (int dx = 0; dx < 3; ++dx) {
      int t = dy*3 + dx;
      int pt0 = prow + ln + dx;
      int dwb = pt0*16 + ((g ^ HS(pt0)) << 2);
      short8v b0 = *(const short8v*)&xk[dwb];
      short8v b1 = *(const short8v*)&xk[dwb + 256];   // pt0+16: HS invariant
      acc0 = __builtin_amdgcn_mfma_f32_16x16x32_bf16(a[t], b0, acc0, 0, 0, 0);
      acc1 = __builtin_amdgcn_mfma_f32_16x16x32_bf16(a[t], b1, acc1, 0, 0, 0);
    }
  }

  const float* bb = biases + (f*P_ + p)*8 + (g & 1)*4;
  float b0v = bb[0], b1v = bb[1], b2v = bb[2], b3v = bb[3];
  uint4 yp;
  yp.x = pk_bf16(fast_tanh(acc0[0] + b0v), fast_tanh(acc0[1] + b1v));
  yp.y = pk_bf16(fast_tanh(acc0[2] + b2v), fast_tanh(acc0[3] + b3v));
  yp.z = pk_bf16(fast_tanh(acc1[0] + b0v), fast_tanh(acc1[1] + b1v));
  yp.w = pk_bf16(fast_tanh(acc1[2] + b2v), fast_tanh(acc1[3] + b3v));
  return yp;
}

template<int MODE>
__global__ __launch_bounds__(256, 4)
void fused_kernel(const void* __restrict__ xsrc_,
                  void* __restrict__ xdst_,
                  const float* __restrict__ state,
                  const u16* __restrict__ Apack,
                  const float* __restrict__ biases,
                  const float* __restrict__ mixb,
                  const float* __restrict__ pal,
                  const float* __restrict__ gw,
                  const float* __restrict__ gb,
                  int p) {
  __shared__ __align__(16) u32 xk[TPTS * 16];     // 13056 B
  __shared__ __align__(16) float obuf[4][16*36];  // 9216 B per-wave f32 buffers

  int bid = blockIdx.x;
  int yt = bid & 7;
  int zt = (bid >> 3) & 15;
  int b  =  bid >> 7;
  int z0 = zt * 2, y0 = yt * 4;
  int tid  = threadIdx.x;
  int lane = tid & 63;
  int wid  = tid >> 6;
  int g    = lane >> 4;
  int ln   = lane & 15;

  // zero x-halo points (x'=0,1): 6 rows x 2 pts x 16 dwords = 192
  if (tid < 192) {
    int pt = (tid >> 5) * 34 + ((tid >> 4) & 1);
    xk[pt*16 + (tid & 15)] = 0u;
  }

  uint4 yp0 = field_step<MODE>(0, xsrc_, Apack, biases, p, b, z0, y0, xk, tid, lane, wid, g, ln);
  uint4 yp1 = field_step<MODE>(1, xsrc_, Apack, biases, p, b, z0, y0, xk, tid, lane, wid, g, ln);
  uint4 yp2 = field_step<MODE>(2, xsrc_, Apack, biases, p, b, z0, y0, xk, tid, lane, wid, g, ln);
  uint4 yp3 = field_step<MODE>(3, xsrc_, Apack, biases, p, b, z0, y0, xk, tid, lane, wid, g, ln);
  uint4 yp4 = field_step<MODE>(4, xsrc_, Apack, biases, p, b, z0, y0, xk, tid, lane, wid, g, ln);
  uint4 yp5 = field_step<MODE>(5, xsrc_, Apack, biases, p, b, z0, y0, xk, tid, lane, wid, g, ln);
  uint4 yp6 = field_step<MODE>(6, xsrc_, Apack, biases, p, b, z0, y0, xk, tid, lane, wid, g, ln);
  uint4 yp7 = field_step<MODE>(7, xsrc_, Apack, biases, p, b, z0, y0, xk, tid, lane, wid, g, ln);

  // ---- epilogue: mix (y kept PACKED; unpack on the fly), residual (+gate),
  //      LDS-transpose to dense 64 B rows, store ----
  float alpha = fast_sig(pal[p]);
  float na = 1.f - alpha;
  int zoff = g >> 1;
  int i0 = (g & 1)*4;
  size_t ebase = (size_t)b*SB_ + (size_t)(z0 + zoff)*1024 + (size_t)(y0 + wid)*32 + ln;

  // store-phase role: row = comp*2+z (16 rows of 32 x), 4 lanes per row
  float* ob = &obuf[wid][0];            // rows stride 36 f32 (2-way max aliasing)
  int srow = lane >> 2;
  int sc   = srow >> 1, sz = srow & 1;
  int sx   = (lane & 3) * 8;
  size_t sbase = (size_t)b*SB_ + (size_t)sc*G3_ + (size_t)(z0 + sz)*1024
               + (size_t)(y0 + wid)*32 + sx;

  #pragma unroll
  for (int gg = 0; gg < 8; ++gg) {
    const float* mr = mixb + (p*8 + gg)*8;
    float o[8] = {0.f,0.f,0.f,0.f,0.f,0.f,0.f,0.f};
    // unpack-on-the-fly mix: no yf[8][8] array -> no spill
    #define MIXF(F, YPV) { \
      float m = mr[F]; \
      o[0] = fmaf(m, bl(YPV.x), o[0]); o[1] = fmaf(m, bh(YPV.x), o[1]); \
      o[2] = fmaf(m, bl(YPV.y), o[2]); o[3] = fmaf(m, bh(YPV.y), o[3]); \
      o[4] = fmaf(m, bl(YPV.z), o[4]); o[5] = fmaf(m, bh(YPV.z), o[5]); \
      o[6] = fmaf(m, bl(YPV.w), o[6]); o[7] = fmaf(m, bh(YPV.w), o[7]); }
    MIXF(0, yp0) MIXF(1, yp1) MIXF(2, yp2) MIXF(3, yp3)
    MIXF(4, yp4) MIXF(5, yp5) MIXF(6, yp6) MIXF(7, yp7)
    #undef MIXF

    size_t og = ebase + (size_t)gg*SF_;

    // residual read + combine + scatter f32 into per-wave LDS rows
    #pragma unroll
    for (int e = 0; e < 8; ++e) {
      size_t idx = og + (size_t)(i0 + (e & 3))*G3_ + ((e >> 2) << 4);
      float xbv;
      if (MODE == 0) xbv = ((const float*)xsrc_)[idx];
      else           xbv = b16f(((const u16*)xsrc_)[idx]);
      float xf = alpha*xbv + na*o[e];
      if (MODE == 2) {
        float st = state[idx];
        float w  = gw[gg*8 + i0 + (e & 3)];
        float bv = gb[gg*8 + i0 + (e & 3)];
        float gt = fast_sig(w*st + bv);
        xf = gt*st + (1.f - gt)*xf;
      }
      ob[((i0 + (e & 3))*2 + zoff)*36 + ln + ((e >> 2) << 4)] = xf;
    }
    // wave-local ds ops are in-order: read back row-linear, store dense 64 B
    float4 v0 = *(const float4*)&ob[srow*36 + sx];
    float4 v1 = *(const float4*)&ob[srow*36 + sx + 4];
    if (MODE == 2) {
      float* op = (float*)xdst_ + sbase + (size_t)gg*SF_;
      *(float4*)(op)     = v0;
      *(float4*)(op + 4) = v1;
    } else {
      uint4 w;
      w.x = pk_bf16(v0.x, v0.y);
      w.y = pk_bf16(v0.z, v0.w);
      w.z = pk_bf16(v1.x, v1.y);
      w.w = pk_bf16(v1.z, v1.w);
      *(uint4*)((u16*)xdst_ + sbase + (size_t)gg*SF_) = w;
    }
  }
}

// ---------------------------------------------------------------------------
extern "C" void kernel_launch(void* const* d_in, const int* in_sizes, int n_in,
                              void* d_out, int out_size, void* d_ws, size_t ws_size,
                              hipStream_t stream) {
  (void)in_sizes; (void)n_in; (void)out_size; (void)ws_size;
  const float* state       = (const float*)d_in[0];
  const float* all_weights = (const float*)d_in[1];
  const float* all_biases  = (const float*)d_in[2];
  const float* mix_logits  = (const float*)d_in[3];
  const float* pal         = (const float*)d_in[4];
  const float* gw          = (const float*)d_in[5];
  const float* gb          = (const float*)d_in[6];
  float* out = (float*)d_out;

  // ws: X0 bf16 (N_) | X1 bf16 (N_) | Apack | mix
  u16* X0 = (u16*)d_ws;
  u16* X1 = X0 + N_;
  u16* Apack = X1 + N_;
  float* mixb = (float*)(Apack + APACK_SZ);

  prep_kernel<<<dim3(APACK_SZ/256), dim3(256), 0, stream>>>(
      all_weights, mix_logits, Apack, mixb);

  dim3 grid(2048), blk(256);
  // p0: state(f32) -> X0 ; p1: X0 -> X1 ; p2: X1 -> X0 ; p3: X0 (+state) -> out
  fused_kernel<0><<<grid, blk, 0, stream>>>((const void*)state, (void*)X0, state,
      Apack, all_biases, mixb, pal, gw, gb, 0);
  fused_kernel<1><<<grid, blk, 0, stream>>>((const void*)X0, (void*)X1, state,
      Apack, all_biases, mixb, pal, gw, gb, 1);
  fused_kernel<1><<<grid, blk, 0, stream>>>((const void*)X1, (void*)X0, state,
      Apack, all_biases, mixb, pal, gw, gb, 2);
  fused_kernel<2><<<grid, blk, 0, stream>>>((const void*)X0, (void*)out, state,
      Apack, all_biases, mixb, pal, gw, gb, 3);
}

// Round 12
// 292.948 us; speedup vs baseline: 2.8786x; 1.0437x over previous
//
#include <hip/hip_runtime.h>
#include <math.h>

// Problem constants
#define B_  16
#define F_  8
#define C_  8
#define G_  32
#define G3_ 32768
#define P_  4
#define N_  (B_*F_*C_*G3_)
#define SF_ (C_*G3_)
#define SB_ (F_*SF_)
#define APACK_SZ (P_*F_*9*64*8)

typedef __attribute__((ext_vector_type(8))) short short8v;
typedef __attribute__((ext_vector_type(4))) float f32x4;
typedef unsigned short u16;
typedef unsigned int u32;

__device__ __constant__ int c_k[8][8] = {
  {0,1,2,3,4,5,6,7},
  {1,0,4,5,2,3,7,6},
  {2,4,0,6,1,7,3,5},
  {3,5,6,0,7,1,2,4},
  {4,2,1,7,0,6,5,3},
  {5,3,7,1,6,0,4,2},
  {6,7,3,2,5,4,0,1},
  {7,6,5,4,3,2,1,0}};
__device__ __constant__ float c_s[8][8] = {
  { 1, 1, 1, 1,-1,-1,-1,-1},
  { 1, 1, 1, 1,-1,-1,-1,-1},
  { 1,-1, 1, 1, 1, 1,-1, 1},
  { 1,-1,-1, 1,-1, 1, 1,-1},
  { 1,-1, 1, 1, 1, 1,-1, 1},
  { 1,-1,-1, 1,-1, 1, 1,-1},
  { 1, 1,-1, 1, 1,-1, 1, 1},
  { 1, 1,-1, 1, 1,-1, 1, 1}};

__device__ __forceinline__ float fast_tanh(float v) {
  float e = __expf(2.f * v);
  return 1.f - 2.f / (e + 1.f);
}
__device__ __forceinline__ float fast_sig(float v) {
  return 1.f / (1.f + __expf(-v));
}
__device__ __forceinline__ u32 bf16_rne(float v) {
  u32 u = __float_as_uint(v);
  return (u + 0x7FFFu + ((u >> 16) & 1u)) >> 16;
}
__device__ __forceinline__ u32 pk_bf16(float a, float b) {
  u32 d;
  asm("v_cvt_pk_bf16_f32 %0, %1, %2" : "=v"(d) : "v"(a), "v"(b));
  return d;
}
__device__ __forceinline__ float bl(u32 u) { return __uint_as_float(u << 16); }
__device__ __forceinline__ float bh(u32 u) { return __uint_as_float(u & 0xffff0000u); }

// position swizzle: quad qq of point pt stored at (qq ^ HS(pt)); HS(pt+16)==HS(pt)
#define HS(pt) (((pt) + ((pt) >> 2)) & 3)
#define OSTR 34      // obuf row stride (f32): scatter 2-way, readback ~2-way

// ---------------------------------------------------------------------------
// prep: A fragments in per-lane MFMA layout + softmax mix
__global__ void prep_kernel(const float* __restrict__ all_weights,
                            const float* __restrict__ mix_logits,
                            u16* __restrict__ Apack,
                            float* __restrict__ mix) {
  int idx = blockIdx.x * 256 + threadIdx.x;
  if (idx < APACK_SZ) {
    int e = idx & 7;
    int l = (idx >> 3) & 63;
    int rest = idx >> 9;
    int t = rest % 9;
    int fp = rest / 9;
    int f = fp & 7, p = fp >> 3;
    int g = l >> 4, m = l & 15;
    int zoff = m >> 3, i = m & 7;
    int kk = g*4 + (e & 3) + ((e >= 4) ? 16 : 0);
    int zl = kk >> 3, j = kk & 7;
    int dz = zl - zoff;
    float val = 0.f;
    if (dz >= 0 && dz <= 2)
      val = c_s[i][j] * all_weights[((f*P_ + p)*27 + (dz*9 + t))*8 + c_k[i][j]];
    Apack[idx] = (u16)bf16_rne(val);
  }
  if (blockIdx.x == 0 && threadIdx.x < P_*F_) {
    int p = threadIdx.x / F_, g = threadIdx.x % F_;
    const float* row = &mix_logits[(p*F_ + g)*F_];
    float mx = row[0];
    for (int f = 1; f < F_; ++f) mx = fmaxf(mx, row[f]);
    float e[F_]; float sum = 0.f;
    for (int f = 0; f < F_; ++f) { e[f] = __expf(row[f] - mx); sum += e[f]; }
    float inv = 1.f / sum;
    for (int f = 0; f < F_; ++f) mix[(p*F_ + g)*F_ + f] = e[f] * inv;
  }
}

// ---------------------------------------------------------------------------
// Fused conv+tanh+mix(+gate).  Block: (b, z-pair, y-tile of 4), ALL 8 fields.
// Planar bf16 X layout [b][f][comp][z][y][x].
// MODE 0: f32 in, bf16 out; 1: bf16->bf16; 2: bf16 in, gate, f32 out.
#define TPTS 204     // 6*34

template<int MODE>
__device__ __forceinline__ uint4 field_step(
    int f, const void* __restrict__ xsrc_, const u16* __restrict__ Apack,
    const float* __restrict__ biases, int p, int b, int z0, int y0,
    u32* xk, int tid, int lane, int wid, int g, int ln) {
  if (f) __syncthreads();       // prev field's LDS reads done before overwrite

  // ---- stage field f: 4 qq x 6 rows x 8 chunks of 4 x-points ----
  if (tid < 192) {
    int qq  = tid / 48;
    int r2  = tid - qq*48;
    int row = r2 >> 3;
    int c   = r2 & 7;
    int zl = qq >> 1, jq = qq & 1;
    int gz0 = z0 - 2 + zl;             // may be <0; gz0+2 always valid
    int gy  = y0 - 2 + row;            // may be <0
    int gx  = c * 4;
    int off = (jq*4)*G3_ + gz0*1024 + gy*32 + gx;
    int ptb = row*34 + 2 + gx;
    u32 d0[4], d1[4], d2[4], d3[4];
    if (MODE != 0) {
      const u16* s0 = (const u16*)xsrc_ + (size_t)b*SB_ + f*SF_ + off;
      const u16* s1 = s0 + 2048;
      uint2 a0={0,0},a1={0,0},a2={0,0},a3={0,0};
      uint2 e0={0,0},e1={0,0},e2={0,0},e3={0,0};
      if (gy >= 0) {
        if (gz0 >= 0) {
          a0 = *(const uint2*)(s0);
          a1 = *(const uint2*)(s0 + G3_);
          a2 = *(const uint2*)(s0 + 2*G3_);
          a3 = *(const uint2*)(s0 + 3*G3_);
        }
        e0 = *(const uint2*)(s1);
        e1 = *(const uint2*)(s1 + G3_);
        e2 = *(const uint2*)(s1 + 2*G3_);
        e3 = *(const uint2*)(s1 + 3*G3_);
      }
      d0[0] = __builtin_amdgcn_perm(a1.x, a0.x, 0x05040100u);
      d0[1] = __builtin_amdgcn_perm(a1.x, a0.x, 0x07060302u);
      d0[2] = __builtin_amdgcn_perm(a1.y, a0.y, 0x05040100u);
      d0[3] = __builtin_amdgcn_perm(a1.y, a0.y, 0x07060302u);
      d1[0] = __builtin_amdgcn_perm(a3.x, a2.x, 0x05040100u);
      d1[1] = __builtin_amdgcn_perm(a3.x, a2.x, 0x07060302u);
      d1[2] = __builtin_amdgcn_perm(a3.y, a2.y, 0x05040100u);
      d1[3] = __builtin_amdgcn_perm(a3.y, a2.y, 0x07060302u);
      d2[0] = __builtin_amdgcn_perm(e1.x, e0.x, 0x05040100u);
      d2[1] = __builtin_amdgcn_perm(e1.x, e0.x, 0x07060302u);
      d2[2] = __builtin_amdgcn_perm(e1.y, e0.y, 0x05040100u);
      d2[3] = __builtin_amdgcn_perm(e1.y, e0.y, 0x07060302u);
      d3[0] = __builtin_amdgcn_perm(e3.x, e2.x, 0x05040100u);
      d3[1] = __builtin_amdgcn_perm(e3.x, e2.x, 0x07060302u);
      d3[2] = __builtin_amdgcn_perm(e3.y, e2.y, 0x05040100u);
      d3[3] = __builtin_amdgcn_perm(e3.y, e2.y, 0x07060302u);
    } else {
      const float* s0 = (const float*)xsrc_ + (size_t)b*SB_ + f*SF_ + off;
      const float* s1 = s0 + 2048;
      float4 A0={0,0,0,0},A1={0,0,0,0},A2={0,0,0,0},A3={0,0,0,0};
      float4 B0={0,0,0,0},B1={0,0,0,0},B2={0,0,0,0},B3={0,0,0,0};
      if (gy >= 0) {
        if (gz0 >= 0) {
          A0 = *(const float4*)(s0);
          A1 = *(const float4*)(s0 + G3_);
          A2 = *(const float4*)(s0 + 2*G3_);
          A3 = *(const float4*)(s0 + 3*G3_);
        }
        B0 = *(const float4*)(s1);
        B1 = *(const float4*)(s1 + G3_);
        B2 = *(const float4*)(s1 + 2*G3_);
        B3 = *(const float4*)(s1 + 3*G3_);
      }
      d0[0]=pk_bf16(A0.x,A1.x); d1[0]=pk_bf16(A2.x,A3.x);
      d2[0]=pk_bf16(B0.x,B1.x); d3[0]=pk_bf16(B2.x,B3.x);
      d0[1]=pk_bf16(A0.y,A1.y); d1[1]=pk_bf16(A2.y,A3.y);
      d2[1]=pk_bf16(B0.y,B1.y); d3[1]=pk_bf16(B2.y,B3.y);
      d0[2]=pk_bf16(A0.z,A1.z); d1[2]=pk_bf16(A2.z,A3.z);
      d2[2]=pk_bf16(B0.z,B1.z); d3[2]=pk_bf16(B2.z,B3.z);
      d0[3]=pk_bf16(A0.w,A1.w); d1[3]=pk_bf16(A2.w,A3.w);
      d2[3]=pk_bf16(B0.w,B1.w); d3[3]=pk_bf16(B2.w,B3.w);
    }
    #define STW(px) { \
      uint4 d; d.x = d0[px]; d.y = d1[px]; d.z = d2[px]; d.w = d3[px]; \
      int pt = ptb + px; \
      *(uint4*)&xk[pt*16 + ((qq ^ HS(pt)) << 2)] = d; }
    STW(0) STW(1) STW(2) STW(3)
    #undef STW
  }

  // A fragments for this field (overlaps barrier wait)
  short8v a[9];
  const u16* ap = Apack + (size_t)((p*8 + f) * 9) * 512;
  #pragma unroll
  for (int t = 0; t < 9; ++t)
    a[t] = *(const short8v*)(ap + (t*64 + lane)*8);

  __syncthreads();

  // ---- compute: wave wid owns y row wid, both x halves ----
  f32x4 acc0 = {0.f,0.f,0.f,0.f}, acc1 = {0.f,0.f,0.f,0.f};
  #pragma unroll
  for (int dy = 0; dy < 3; ++dy) {
    int prow = (wid + dy)*34;
    #pragma unroll
    for (int dx = 0; dx < 3; ++dx) {
      int t = dy*3 + dx;
      int pt0 = prow + ln + dx;
      int dwb = pt0*16 + ((g ^ HS(pt0)) << 2);
      short8v b0 = *(const short8v*)&xk[dwb];
      short8v b1 = *(const short8v*)&xk[dwb + 256];   // pt0+16: HS invariant
      acc0 = __builtin_amdgcn_mfma_f32_16x16x32_bf16(a[t], b0, acc0, 0, 0, 0);
      acc1 = __builtin_amdgcn_mfma_f32_16x16x32_bf16(a[t], b1, acc1, 0, 0, 0);
    }
  }

  const float* bb = biases + (f*P_ + p)*8 + (g & 1)*4;
  float b0v = bb[0], b1v = bb[1], b2v = bb[2], b3v = bb[3];
  uint4 yp;
  yp.x = pk_bf16(fast_tanh(acc0[0] + b0v), fast_tanh(acc0[1] + b1v));
  yp.y = pk_bf16(fast_tanh(acc0[2] + b2v), fast_tanh(acc0[3] + b3v));
  yp.z = pk_bf16(fast_tanh(acc1[0] + b0v), fast_tanh(acc1[1] + b1v));
  yp.w = pk_bf16(fast_tanh(acc1[2] + b2v), fast_tanh(acc1[3] + b3v));
  return yp;
}

template<int MODE>
__global__ __launch_bounds__(256, 4)
void fused_kernel(const void* __restrict__ xsrc_,
                  void* __restrict__ xdst_,
                  const float* __restrict__ state,
                  const u16* __restrict__ Apack,
                  const float* __restrict__ biases,
                  const float* __restrict__ mixb,
                  const float* __restrict__ pal,
                  const float* __restrict__ gw,
                  const float* __restrict__ gb,
                  int p) {
  __shared__ __align__(16) u32 xk[TPTS * 16];       // 13056 B
  __shared__ __align__(16) float obuf[4][16*OSTR];  // 8704 B per-wave f32 buffers

  int bid = blockIdx.x;
  int yt = bid & 7;
  int zt = (bid >> 3) & 15;
  int b  =  bid >> 7;
  int z0 = zt * 2, y0 = yt * 4;
  int tid  = threadIdx.x;
  int lane = tid & 63;
  int wid  = tid >> 6;
  int g    = lane >> 4;
  int ln   = lane & 15;

  // zero x-halo points (x'=0,1): 6 rows x 2 pts x 16 dwords = 192
  if (tid < 192) {
    int pt = (tid >> 5) * 34 + ((tid >> 4) & 1);
    xk[pt*16 + (tid & 15)] = 0u;
  }

  uint4 yp0 = field_step<MODE>(0, xsrc_, Apack, biases, p, b, z0, y0, xk, tid, lane, wid, g, ln);
  uint4 yp1 = field_step<MODE>(1, xsrc_, Apack, biases, p, b, z0, y0, xk, tid, lane, wid, g, ln);
  uint4 yp2 = field_step<MODE>(2, xsrc_, Apack, biases, p, b, z0, y0, xk, tid, lane, wid, g, ln);
  uint4 yp3 = field_step<MODE>(3, xsrc_, Apack, biases, p, b, z0, y0, xk, tid, lane, wid, g, ln);
  uint4 yp4 = field_step<MODE>(4, xsrc_, Apack, biases, p, b, z0, y0, xk, tid, lane, wid, g, ln);
  uint4 yp5 = field_step<MODE>(5, xsrc_, Apack, biases, p, b, z0, y0, xk, tid, lane, wid, g, ln);
  uint4 yp6 = field_step<MODE>(6, xsrc_, Apack, biases, p, b, z0, y0, xk, tid, lane, wid, g, ln);
  uint4 yp7 = field_step<MODE>(7, xsrc_, Apack, biases, p, b, z0, y0, xk, tid, lane, wid, g, ln);

  // ---- epilogue: mix (y packed, unpack on the fly) -> LDS transpose ->
  //      dense residual read (+gate) -> dense store ----
  float alpha = fast_sig(pal[p]);
  float na = 1.f - alpha;
  int zoff = g >> 1;
  int i0 = (g & 1)*4;

  // store-phase role: row = comp*2+z (16 rows of 32 x), 4 lanes per row
  float* ob = &obuf[wid][0];
  int srow = lane >> 2;
  int sc   = srow >> 1, sz = srow & 1;
  int sx   = (lane & 3) * 8;
  size_t sbase = (size_t)b*SB_ + (size_t)sc*G3_ + (size_t)(z0 + sz)*1024
               + (size_t)(y0 + wid)*32 + sx;

  #pragma unroll
  for (int gg = 0; gg < 8; ++gg) {
    const float* mr = mixb + (p*8 + gg)*8;
    float o[8] = {0.f,0.f,0.f,0.f,0.f,0.f,0.f,0.f};
    // unpack-on-the-fly mix: no yf[8][8] array -> no spill
    #define MIXF(F, YPV) { \
      float m = mr[F]; \
      o[0] = fmaf(m, bl(YPV.x), o[0]); o[1] = fmaf(m, bh(YPV.x), o[1]); \
      o[2] = fmaf(m, bl(YPV.y), o[2]); o[3] = fmaf(m, bh(YPV.y), o[3]); \
      o[4] = fmaf(m, bl(YPV.z), o[4]); o[5] = fmaf(m, bh(YPV.z), o[5]); \
      o[6] = fmaf(m, bl(YPV.w), o[6]); o[7] = fmaf(m, bh(YPV.w), o[7]); }
    MIXF(0, yp0) MIXF(1, yp1) MIXF(2, yp2) MIXF(3, yp3)
    MIXF(4, yp4) MIXF(5, yp5) MIXF(6, yp6) MIXF(7, yp7)
    #undef MIXF

    // scatter mix result into per-wave LDS rows (wave-local, in-order)
    #pragma unroll
    for (int e = 0; e < 8; ++e)
      ob[((i0 + (e & 3))*2 + zoff)*OSTR + ln + ((e >> 2) << 4)] = o[e];

    // read back row-linear (dense 64 B per 4-lane group)
    float4 m0 = *(const float4*)&ob[srow*OSTR + sx];
    float4 m1 = *(const float4*)&ob[srow*OSTR + sx + 4];

    size_t sidx = sbase + (size_t)gg*SF_;
    float xb[8], xf[8];
    if (MODE == 0) {
      const float* xsp = (const float*)xsrc_ + sidx;
      float4 x0 = *(const float4*)(xsp);
      float4 x1 = *(const float4*)(xsp + 4);
      xb[0]=x0.x; xb[1]=x0.y; xb[2]=x0.z; xb[3]=x0.w;
      xb[4]=x1.x; xb[5]=x1.y; xb[6]=x1.z; xb[7]=x1.w;
    } else {
      uint4 u = *(const uint4*)((const u16*)xsrc_ + sidx);
      xb[0]=bl(u.x); xb[1]=bh(u.x); xb[2]=bl(u.y); xb[3]=bh(u.y);
      xb[4]=bl(u.z); xb[5]=bh(u.z); xb[6]=bl(u.w); xb[7]=bh(u.w);
    }
    float mv[8] = {m0.x,m0.y,m0.z,m0.w, m1.x,m1.y,m1.z,m1.w};
    #pragma unroll
    for (int e = 0; e < 8; ++e) xf[e] = alpha*xb[e] + na*mv[e];

    if (MODE == 2) {
      const float* stp = state + sidx;
      float4 s0 = *(const float4*)(stp);
      float4 s1 = *(const float4*)(stp + 4);
      float st[8] = {s0.x,s0.y,s0.z,s0.w, s1.x,s1.y,s1.z,s1.w};
      float w  = gw[gg*8 + sc];
      float bv = gb[gg*8 + sc];
      float r[8];
      #pragma unroll
      for (int e = 0; e < 8; ++e) {
        float gt = fast_sig(w*st[e] + bv);
        r[e] = gt*st[e] + (1.f - gt)*xf[e];
      }
      float* op = (float*)xdst_ + sidx;
      *(float4*)(op)     = make_float4(r[0],r[1],r[2],r[3]);
      *(float4*)(op + 4) = make_float4(r[4],r[5],r[6],r[7]);
    } else {
      uint4 w;
      w.x = pk_bf16(xf[0], xf[1]);
      w.y = pk_bf16(xf[2], xf[3]);
      w.z = pk_bf16(xf[4], xf[5]);
      w.w = pk_bf16(xf[6], xf[7]);
      *(uint4*)((u16*)xdst_ + sidx) = w;
    }
  }
}

// ---------------------------------------------------------------------------
extern "C" void kernel_launch(void* const* d_in, const int* in_sizes, int n_in,
                              void* d_out, int out_size, void* d_ws, size_t ws_size,
                              hipStream_t stream) {
  (void)in_sizes; (void)n_in; (void)out_size; (void)ws_size;
  const float* state       = (const float*)d_in[0];
  const float* all_weights = (const float*)d_in[1];
  const float* all_biases  = (const float*)d_in[2];
  const float* mix_logits  = (const float*)d_in[3];
  const float* pal         = (const float*)d_in[4];
  const float* gw          = (const float*)d_in[5];
  const float* gb          = (const float*)d_in[6];
  float* out = (float*)d_out;

  // ws: X0 bf16 (N_) | X1 bf16 (N_) | Apack | mix
  u16* X0 = (u16*)d_ws;
  u16* X1 = X0 + N_;
  u16* Apack = X1 + N_;
  float* mixb = (float*)(Apack + APACK_SZ);

  prep_kernel<<<dim3(APACK_SZ/256), dim3(256), 0, stream>>>(
      all_weights, mix_logits, Apack, mixb);

  dim3 grid(2048), blk(256);
  // p0: state(f32) -> X0 ; p1: X0 -> X1 ; p2: X1 -> X0 ; p3: X0 (+state) -> out
  fused_kernel<0><<<grid, blk, 0, stream>>>((const void*)state, (void*)X0, state,
      Apack, all_biases, mixb, pal, gw, gb, 0);
  fused_kernel<1><<<grid, blk, 0, stream>>>((const void*)X0, (void*)X1, state,
      Apack, all_biases, mixb, pal, gw, gb, 1);
  fused_kernel<1><<<grid, blk, 0, stream>>>((const void*)X1, (void*)X0, state,
      Apack, all_biases, mixb, pal, gw, gb, 2);
  fused_kernel<2><<<grid, blk, 0, stream>>>((const void*)X0, (void*)out, state,
      Apack, all_biases, mixb, pal, gw, gb, 3);
}